// Round 9
// baseline (625.927 us; speedup 1.0000x reference)
//
#include <hip/hip_runtime.h>
#include <hip/hip_bf16.h>

#define D 768
#define NQ 64
#define RT 16                 // corpus rows per tile
#define SIMGRID 256
#define SIMTPB 256            // 4 waves = 4 qf
#define KSTEPS 24
#define NMW 4096              // mergeA lists per query
#define NS 8                  // merge1 segments per query
#define CANDCAP 256
#define MARGIN 4e-3f

#define QLDS 98304            // 24*4*64*8 halves * 2B
#define CTILE 24576           // 16 rows * 768 halves * 2B
#define LDS_BYTES (QLDS + 2 * CTILE + 2 * RT * 4)   // 147584

typedef float    f32x4 __attribute__((ext_vector_type(4)));
typedef _Float16 h16x8 __attribute__((ext_vector_type(8)));

typedef const void __attribute__((address_space(1)))* gas_ptr;
typedef void __attribute__((address_space(3)))* las_ptr;

__device__ __forceinline__ unsigned short f2bf(float f) {
    unsigned int u = __float_as_uint(f);
    return (unsigned short)((u + 0x7fffu + ((u >> 16) & 1u)) >> 16);   // RNE
}
__device__ __forceinline__ float bf2f(unsigned short b) {
    return __uint_as_float(((unsigned int)b) << 16);
}

// ---------- float top-k helpers (static-indexed: stays in VGPRs) ----------
__device__ __forceinline__ bool kbetter(float v1, int i1, float v2, int i2) {
    return (v1 > v2) || (v1 == v2 && i1 < i2);
}

__device__ __forceinline__ void topk_insert(float (&tv)[16], int (&ti)[16], float v, int idx) {
    if (!kbetter(v, idx, tv[15], ti[15])) return;
    tv[15] = v; ti[15] = idx;
    #pragma unroll
    for (int s = 15; s >= 1; --s) {
        bool sw = kbetter(tv[s], ti[s], tv[s-1], ti[s-1]);
        float av = sw ? tv[s] : tv[s-1];
        float bv = sw ? tv[s-1] : tv[s];
        int   ai = sw ? ti[s] : ti[s-1];
        int   bi = sw ? ti[s-1] : ti[s];
        tv[s-1] = av; tv[s] = bv; ti[s-1] = ai; ti[s] = bi;
    }
}

__device__ __forceinline__ void bitonic16(float (&v)[16], int (&ix)[16]) {
    #pragma unroll
    for (int d = 8; d >= 1; d >>= 1) {
        #pragma unroll
        for (int i = 0; i < 16; ++i) {
            if ((i & d) == 0) {
                int j = i | d;
                bool sw = kbetter(v[j], ix[j], v[i], ix[i]);
                float av = sw ? v[j] : v[i];
                float bv = sw ? v[i] : v[j];
                int   ai = sw ? ix[j] : ix[i];
                int   bi = sw ? ix[i] : ix[j];
                v[i] = av; v[j] = bv; ix[i] = ai; ix[j] = bi;
            }
        }
    }
}

__device__ __forceinline__ void lane_merge(float (&v)[16], int (&ix)[16], int mask) {
    float pv[16]; int pix[16];
    #pragma unroll
    for (int i = 0; i < 16; ++i) {
        pv[i]  = __shfl_xor(v[15 - i], mask);
        pix[i] = __shfl_xor(ix[15 - i], mask);
    }
    #pragma unroll
    for (int i = 0; i < 16; ++i) {
        if (kbetter(pv[i], pix[i], v[i], ix[i])) { v[i] = pv[i]; ix[i] = pix[i]; }
    }
    bitonic16(v, ix);
}

__device__ __forceinline__ void sort64(float& v, int& ix, int l) {
    #pragma unroll
    for (int k = 2; k <= 64; k <<= 1) {
        #pragma unroll
        for (int j = k >> 1; j >= 1; j >>= 1) {
            float ov = __shfl_xor(v, j);
            int   oi = __shfl_xor(ix, j);
            bool dirDesc = ((l & k) == 0);
            bool lower   = ((l & j) == 0);
            bool takeBetter = (lower == dirDesc);
            bool ob = kbetter(ov, oi, v, ix);
            if (takeBetter == ob) { v = ov; ix = oi; }
        }
    }
}

// ---------- double top-k (exact pass) ----------
__device__ __forceinline__ bool kbetterD(double v1, int i1, double v2, int i2) {
    return (v1 > v2) || (v1 == v2 && i1 < i2);
}

__device__ __forceinline__ void topk_insertD(double (&tv)[16], int (&ti)[16], double v, int idx) {
    if (!kbetterD(v, idx, tv[15], ti[15])) return;
    tv[15] = v; ti[15] = idx;
    #pragma unroll
    for (int s = 15; s >= 1; --s) {
        bool sw = kbetterD(tv[s], ti[s], tv[s-1], ti[s-1]);
        double av = sw ? tv[s] : tv[s-1];
        double bv = sw ? tv[s-1] : tv[s];
        int    ai = sw ? ti[s] : ti[s-1];
        int    bi = sw ? ti[s-1] : ti[s];
        tv[s-1] = av; tv[s] = bv; ti[s-1] = ai; ti[s] = bi;
    }
}

__device__ __forceinline__ void bitonic16D(double (&v)[16], int (&ix)[16]) {
    #pragma unroll
    for (int d = 8; d >= 1; d >>= 1) {
        #pragma unroll
        for (int i = 0; i < 16; ++i) {
            if ((i & d) == 0) {
                int j = i | d;
                bool sw = kbetterD(v[j], ix[j], v[i], ix[i]);
                double av = sw ? v[j] : v[i];
                double bv = sw ? v[i] : v[j];
                int    ai = sw ? ix[j] : ix[i];
                int    bi = sw ? ix[i] : ix[j];
                v[i] = av; v[j] = bv; ix[i] = ai; ix[j] = bi;
            }
        }
    }
}

__device__ __forceinline__ void lane_mergeD(double (&v)[16], int (&ix)[16], int mask) {
    double pv[16]; int pix[16];
    #pragma unroll
    for (int i = 0; i < 16; ++i) {
        pv[i]  = __shfl_xor(v[15 - i], mask);
        pix[i] = __shfl_xor(ix[15 - i], mask);
    }
    #pragma unroll
    for (int i = 0; i < 16; ++i) {
        if (kbetterD(pv[i], pix[i], v[i], ix[i])) { v[i] = pv[i]; ix[i] = pix[i]; }
    }
    bitonic16D(v, ix);
}

// ---------- kernel 0: normalize Q; fp16-hi fragment pack + fp32 rows ----------
// qpk layout: [ks(24)][qf(4)][lane(64)][8 halves]
__global__ __launch_bounds__(256)
void prep_kernel(const float* __restrict__ query, _Float16* __restrict__ qpk,
                 float* __restrict__ qn) {
    int b = blockIdx.x, t = threadIdx.x;
    const float* row = query + b * D;
    float vals[3]; float s = 0.f;
    #pragma unroll
    for (int j = 0; j < 3; ++j) { vals[j] = row[t + 256 * j]; s += vals[j] * vals[j]; }
    #pragma unroll
    for (int m = 1; m < 64; m <<= 1) s += __shfl_xor(s, m);
    __shared__ float ws4[4];
    if ((t & 63) == 0) ws4[t >> 6] = s;
    __syncthreads();
    float qnorm = sqrtf(ws4[0] + ws4[1] + ws4[2] + ws4[3]);
    int qf = b >> 4;
    #pragma unroll
    for (int j = 0; j < 3; ++j) {
        int col = t + 256 * j;
        float vn = vals[j] / qnorm;
        qn[b * D + col] = vn;
        int ks = col >> 5, unit = (col >> 3) & 3, sub = col & 7;
        int lane = (b & 15) + unit * 16;
        qpk[(((size_t)ks * 4 + qf) * 64 + lane) * 8 + sub] = (_Float16)vn;
    }
}

// ---------- kernel 1: contiguous-stream sim pass-1 (fp16-hi, bf16 out) ----------
// Block = 4 waves, 1 block/CU (144KB LDS). Tile = 16 full corpus rows read as one
// contiguous 48KB burst (thread t reads 48 consecutive floats). Double-buffered
// fp16 LDS tile; one barrier per tile; loads issued before compute (T14).
__global__ __launch_bounds__(SIMTPB, 1)
void sim_kernel(const float* __restrict__ corpus,
                const _Float16* __restrict__ qpk,
                unsigned short* __restrict__ simout, int N, int NTILES) {
    extern __shared__ __align__(16) char smem[];
    const _Float16* qlds = (const _Float16*)smem;
    char*  ct = smem + QLDS;
    float* cn = (float*)(smem + QLDS + 2 * CTILE);   // [2][16]

    int t = threadIdx.x, w = t >> 6, l = t & 63;
    int row = t >> 4, seg = t & 15;    // staging: 16 threads per row, 48 floats each
    int qf = w;                        // compute: wave = one 16-query fragment

    // stage Q pack once: 6144 16B granules, linear LDS dest
    #pragma unroll
    for (int j = 0; j < 24; ++j) {
        int idx = t + 256 * j;
        __builtin_amdgcn_global_load_lds((gas_ptr)(const void*)(qpk + (size_t)idx * 8),
                                         (las_ptr)(void*)(smem + (size_t)idx * 16), 16, 0, 0);
    }
    __syncthreads();

    int b = blockIdx.x;
    int q0 = NTILES / SIMGRID, r0 = NTILES % SIMGRID;
    int t0 = b * q0 + min(b, r0);
    int cnt = q0 + (b < r0 ? 1 : 0);

    float4 stg[12];

    auto LOADT = [&](int tile) {
        long grow = (long)tile * RT + row; if (grow > N - 1) grow = N - 1;
        const float* p = corpus + (size_t)grow * D + seg * 48;
        #pragma unroll
        for (int j = 0; j < 12; ++j) stg[j] = *(const float4*)(p + j * 4);
    };

    auto CVTW = [&](int buf) {
        char* base = ct + buf * CTILE;
        float ps = 0.f;
        #pragma unroll
        for (int j = 0; j < 6; ++j) {
            float4 a = stg[2 * j], c = stg[2 * j + 1];
            ps += a.x * a.x + a.y * a.y + a.z * a.z + a.w * a.w;
            ps += c.x * c.x + c.y * c.y + c.z * c.z + c.w * c.w;
            h16x8 hv;
            hv[0] = (_Float16)a.x; hv[1] = (_Float16)a.y; hv[2] = (_Float16)a.z; hv[3] = (_Float16)a.w;
            hv[4] = (_Float16)c.x; hv[5] = (_Float16)c.y; hv[6] = (_Float16)c.z; hv[7] = (_Float16)c.w;
            int off = (row * 1536 + seg * 96 + j * 16) ^ ((row & 7) << 4);
            *(h16x8*)(base + off) = hv;
        }
        ps += __shfl_xor(ps, 1); ps += __shfl_xor(ps, 2);
        ps += __shfl_xor(ps, 4); ps += __shfl_xor(ps, 8);
        if (seg == 0) cn[buf * RT + row] = ps;
    };

    auto COMPUTE = [&](int tile, int buf) {
        const char* base = ct + buf * CTILE;
        f32x4 acc = (f32x4)(0.f);
        #pragma unroll
        for (int ks = 0; ks < KSTEPS; ++ks) {
            h16x8 qh = *(const h16x8*)(qlds + (((size_t)ks * 4 + qf) * 64 + l) * 8);
            int cb = ((l & 15) * 1536 + ks * 64 + (l >> 4) * 16) ^ ((l & 7) << 4);
            h16x8 ch = *(const h16x8*)(base + cb);
            acc = __builtin_amdgcn_mfma_f32_16x16x32_f16(qh, ch, acc, 0, 0, 0);
        }
        int nl = l & 15;
        long n = (long)tile * RT + nl;
        float inv = 1.0f / sqrtf(cn[buf * RT + nl]);
        if (n < N) {
            ushort4 pk;
            pk.x = f2bf(acc[0] * inv); pk.y = f2bf(acc[1] * inv);
            pk.z = f2bf(acc[2] * inv); pk.w = f2bf(acc[3] * inv);
            *(ushort4*)(simout + n * NQ + qf * 16 + (l >> 4) * 4) = pk;
        }
    };

    // prologue: tile 0 staged into buf 0
    LOADT(t0);
    CVTW(0);
    __syncthreads();

    for (int i = 0; i < cnt; ++i) {
        if (i + 1 < cnt) LOADT(t0 + i + 1);    // issue next burst (in flight during compute)
        COMPUTE(t0 + i, i & 1);
        if (i + 1 < cnt) CVTW((i + 1) & 1);    // waits loads under compute shadow; writes other buf
        __syncthreads();                        // waits only LDS writes
    }
}

// ---------- kernel 2: stream bf16 sims -> per-wave per-query top-16 ----------
__global__ __launch_bounds__(256)
void mergeA_kernel(const unsigned short* __restrict__ simout, float2* __restrict__ candA, int N) {
    int t = threadIdx.x, w = t >> 6, l = t & 63;
    int ww = blockIdx.x * 4 + w;
    int chunk = (N + NMW - 1) / NMW;
    int n0 = ww * chunk, n1 = min(N, n0 + chunk);

    float tv[16]; int ti[16];
    #pragma unroll
    for (int s = 0; s < 16; ++s) { tv[s] = -INFINITY; ti[s] = 0x7fffffff; }

    int n = n0;
    for (; n + 8 <= n1; n += 8) {
        float v[8];
        #pragma unroll
        for (int j = 0; j < 8; ++j) v[j] = bf2f(simout[(size_t)(n + j) * NQ + l]);
        #pragma unroll
        for (int j = 0; j < 8; ++j) topk_insert(tv, ti, v[j], n + j);
    }
    for (; n < n1; ++n) topk_insert(tv, ti, bf2f(simout[(size_t)n * NQ + l]), n);

    float2* dst = candA + ((size_t)l * NMW + ww) * 16;
    #pragma unroll
    for (int s = 0; s < 16; ++s) dst[s] = make_float2(tv[s], __int_as_float(ti[s]));
}

// ---------- kernel 3: partial merge — 8 segments per query ----------
__global__ __launch_bounds__(256)
void merge1_kernel(const float2* __restrict__ cand, float2* __restrict__ cand2, int NWV) {
    int q = blockIdx.x >> 3, seg = blockIdx.x & (NS - 1);
    int t = threadIdx.x, w = t >> 6, l = t & 63;
    int total = NWV * 16;
    int chunk = (total + NS - 1) / NS;
    int e0 = seg * chunk, e1 = min(total, e0 + chunk);
    const float2* src = cand + (size_t)q * total;
    float tv[16]; int ti[16];
    #pragma unroll
    for (int s = 0; s < 16; ++s) { tv[s] = -INFINITY; ti[s] = 0x7fffffff; }
    for (int e = e0 + t; e < e1; e += 256) {
        float2 ce = src[e];
        topk_insert(tv, ti, ce.x, __float_as_int(ce.y));
    }
    lane_merge(tv, ti, 1);  lane_merge(tv, ti, 2);  lane_merge(tv, ti, 4);
    lane_merge(tv, ti, 8);  lane_merge(tv, ti, 16); lane_merge(tv, ti, 32);
    __shared__ float2 stage[64];
    if (l == 0) {
        #pragma unroll
        for (int s = 0; s < 16; ++s) stage[w * 16 + s] = make_float2(tv[s], __int_as_float(ti[s]));
    }
    __syncthreads();
    if (t < 64) {
        float2 ce = stage[t];
        float v = ce.x; int ix = __float_as_int(ce.y);
        sort64(v, ix, t);
        if (t < 16) cand2[((size_t)q * NS + seg) * 16 + t] = make_float2(v, __int_as_float(ix));
    }
}

// ---------- kernel 4: approx top-16 -> per-query threshold; zero counters ----------
__global__ __launch_bounds__(64)
void merge2t_kernel(const float2* __restrict__ cand2, float* __restrict__ thr,
                    int* __restrict__ cnt) {
    int q = blockIdx.x, l = threadIdx.x;
    const float2* src = cand2 + (size_t)q * (NS * 16);
    float2 a = src[l], b = src[l + 64];
    float v1 = a.x; int i1 = __float_as_int(a.y);
    float v2 = b.x; int i2 = __float_as_int(b.y);
    sort64(v1, i1, l);
    sort64(v2, i2, l);
    float sv = __shfl(v2, (l - 16) & 63);
    int   si = __shfl(i2, (l - 16) & 63);
    float mv = (l < 16) ? v1 : ((l < 32) ? sv : -INFINITY);
    int   mi = (l < 16) ? i1 : ((l < 32) ? si : 0x7fffffff);
    sort64(mv, mi, l);
    if (l == 15) {
        thr[q] = mv - MARGIN;
        cnt[q] = 0;
    }
}

// ---------- kernel 5: filter — candidates above threshold ----------
__global__ __launch_bounds__(256)
void filter_kernel(const unsigned short* __restrict__ simout, const float* __restrict__ thr,
                   int* __restrict__ cnt, int* __restrict__ candx, int N) {
    int t = threadIdx.x, w = t >> 6, l = t & 63;
    int wid = blockIdx.x * 4 + w;
    int nwaves = gridDim.x * 4;
    float th = thr[l];
    for (int n = wid; n < N; n += nwaves) {
        float v = bf2f(simout[(size_t)n * NQ + l]);
        if (v >= th) {
            int s = atomicAdd(&cnt[l], 1);
            if (s < CANDCAP) candx[l * CANDCAP + s] = n;
        }
    }
}

// ---------- kernel 6: exact fp64 re-rank ----------
__global__ __launch_bounds__(256)
void exact_kernel(const float* __restrict__ corpus, const float* __restrict__ qn,
                  const int* __restrict__ cnt, const int* __restrict__ candx,
                  float* __restrict__ out, int N) {
    int q = blockIdx.x, t = threadIdx.x, w = t >> 6, l = t & 63;
    int m = min(cnt[q], CANDCAP);
    __shared__ double vals[CANDCAP];
    __shared__ int    idxs[CANDCAP];

    const float* qr = qn + q * D;
    for (int c = w; c < m; c += 4) {
        int n = candx[q * CANDCAP + c];
        const float* cr = corpus + (size_t)n * D;
        double acc = 0.0, cs = 0.0;
        #pragma unroll
        for (int j = 0; j < D / 64; ++j) {
            double cv = (double)cr[l + j * 64];
            acc += (double)qr[l + j * 64] * cv;
            cs  += cv * cv;
        }
        #pragma unroll
        for (int msk = 1; msk < 64; msk <<= 1) {
            acc += __shfl_xor(acc, msk);
            cs  += __shfl_xor(cs, msk);
        }
        if (l == 0) { vals[c] = acc / sqrt(cs); idxs[c] = n; }
    }
    __syncthreads();

    if (w == 0) {
        double tv[16]; int ti[16];
        #pragma unroll
        for (int s = 0; s < 16; ++s) { tv[s] = -1e300; ti[s] = 0x7fffffff; }
        for (int r = 0; r < CANDCAP / 64; ++r) {
            int e = l + r * 64;
            if (e < m) topk_insertD(tv, ti, vals[e], idxs[e]);
        }
        lane_mergeD(tv, ti, 1);  lane_mergeD(tv, ti, 2);  lane_mergeD(tv, ti, 4);
        lane_mergeD(tv, ti, 8);  lane_mergeD(tv, ti, 16); lane_mergeD(tv, ti, 32);
        if (l == 0) {
            #pragma unroll
            for (int s = 0; s < 16; ++s) {
                out[q * 16 + s]           = (float)tv[s];
                out[NQ * 16 + q * 16 + s] = (float)ti[s];
            }
        }
    }
}

extern "C" void kernel_launch(void* const* d_in, const int* in_sizes, int n_in,
                              void* d_out, int out_size, void* d_ws, size_t ws_size,
                              hipStream_t stream) {
    const float* query  = (const float*)d_in[0];
    const float* corpus = (const float*)d_in[1];
    int N      = in_sizes[1] / D;                 // 500000
    int NTILES = (N + RT - 1) / RT;               // 31250

    char* ws = (char*)d_ws;
    _Float16* qpk = (_Float16*)ws;                              // 98304 B
    float* qn     = (float*)(ws + 98304);                       // 196608 B
    unsigned short* simout = (unsigned short*)(ws + 98304 + 196608);   // NTILES*16*64*2 = 64 MB
    size_t simBytes = (size_t)NTILES * RT * NQ * sizeof(unsigned short);
    char* p = ws + 98304 + 196608 + simBytes;
    float2* candA = (float2*)p;                                 // 64*4096*16*8 = 33.5 MB
    size_t candABytes = (size_t)NQ * NMW * 16 * sizeof(float2);
    float2* cand2 = (float2*)(p + candABytes);                  // 64 KB
    float*  thr   = (float*)(p + candABytes + 65536);           // 256 B
    int*    cnt   = (int*)(p + candABytes + 65536 + 256);       // 256 B
    int*    candx = (int*)(p + candABytes + 65536 + 512);       // 64*256*4 = 64 KB
    float* out = (float*)d_out;

    (void)hipFuncSetAttribute((const void*)sim_kernel,
                              hipFuncAttributeMaxDynamicSharedMemorySize, LDS_BYTES);

    prep_kernel<<<NQ, 256, 0, stream>>>(query, qpk, qn);
    sim_kernel<<<SIMGRID, SIMTPB, LDS_BYTES, stream>>>(corpus, qpk, simout, N, NTILES);
    mergeA_kernel<<<NMW / 4, 256, 0, stream>>>(simout, candA, N);
    merge1_kernel<<<NQ * NS, 256, 0, stream>>>(candA, cand2, NMW);
    merge2t_kernel<<<NQ, 64, 0, stream>>>(cand2, thr, cnt);
    filter_kernel<<<1024, 256, 0, stream>>>(simout, thr, cnt, candx, N);
    exact_kernel<<<NQ, 256, 0, stream>>>(corpus, qn, cnt, candx, out, N);
}

// Round 10
// 606.714 us; speedup vs baseline: 1.0317x; 1.0317x over previous
//
#include <hip/hip_runtime.h>
#include <hip/hip_bf16.h>

#define D 768
#define NQ 64
#define RT 16                 // corpus rows per tile
#define SIMGRID 256
#define SIMTPB 1024           // 16 waves: (qf = w&3, kq = w>>2)
#define NMW 4096              // mergeA lists per query
#define NS 8                  // merge1 segments per query
#define CANDCAP 256
#define MARGIN 4e-3f

// LDS map (bytes): Q pack 0..98304 | tiles 98304 + buf*24576 (2 bufs)
//                  | scratch 147456 (12 KB) | cn 159744 (128 B)
#define LDS_Q      0
#define LDS_TILE   98304
#define TILE_B     24576
#define LDS_SCR    147456
#define LDS_CN     159744
#define LDS_BYTES  159872

typedef float    f32x4 __attribute__((ext_vector_type(4)));
typedef _Float16 h16x8 __attribute__((ext_vector_type(8)));
typedef _Float16 h16x4 __attribute__((ext_vector_type(4)));

typedef const void __attribute__((address_space(1)))* gas_ptr;
typedef void __attribute__((address_space(3)))* las_ptr;

__device__ __forceinline__ unsigned short f2bf(float f) {
    unsigned int u = __float_as_uint(f);
    return (unsigned short)((u + 0x7fffu + ((u >> 16) & 1u)) >> 16);   // RNE
}
__device__ __forceinline__ float bf2f(unsigned short b) {
    return __uint_as_float(((unsigned int)b) << 16);
}

// ---------- float top-k helpers ----------
__device__ __forceinline__ bool kbetter(float v1, int i1, float v2, int i2) {
    return (v1 > v2) || (v1 == v2 && i1 < i2);
}

__device__ __forceinline__ void topk_insert(float (&tv)[16], int (&ti)[16], float v, int idx) {
    if (!kbetter(v, idx, tv[15], ti[15])) return;
    tv[15] = v; ti[15] = idx;
    #pragma unroll
    for (int s = 15; s >= 1; --s) {
        bool sw = kbetter(tv[s], ti[s], tv[s-1], ti[s-1]);
        float av = sw ? tv[s] : tv[s-1];
        float bv = sw ? tv[s-1] : tv[s];
        int   ai = sw ? ti[s] : ti[s-1];
        int   bi = sw ? ti[s-1] : ti[s];
        tv[s-1] = av; tv[s] = bv; ti[s-1] = ai; ti[s] = bi;
    }
}

__device__ __forceinline__ void bitonic16(float (&v)[16], int (&ix)[16]) {
    #pragma unroll
    for (int d = 8; d >= 1; d >>= 1) {
        #pragma unroll
        for (int i = 0; i < 16; ++i) {
            if ((i & d) == 0) {
                int j = i | d;
                bool sw = kbetter(v[j], ix[j], v[i], ix[i]);
                float av = sw ? v[j] : v[i];
                float bv = sw ? v[i] : v[j];
                int   ai = sw ? ix[j] : ix[i];
                int   bi = sw ? ix[i] : ix[j];
                v[i] = av; v[j] = bv; ix[i] = ai; ix[j] = bi;
            }
        }
    }
}

__device__ __forceinline__ void lane_merge(float (&v)[16], int (&ix)[16], int mask) {
    float pv[16]; int pix[16];
    #pragma unroll
    for (int i = 0; i < 16; ++i) {
        pv[i]  = __shfl_xor(v[15 - i], mask);
        pix[i] = __shfl_xor(ix[15 - i], mask);
    }
    #pragma unroll
    for (int i = 0; i < 16; ++i) {
        if (kbetter(pv[i], pix[i], v[i], ix[i])) { v[i] = pv[i]; ix[i] = pix[i]; }
    }
    bitonic16(v, ix);
}

__device__ __forceinline__ void sort64(float& v, int& ix, int l) {
    #pragma unroll
    for (int k = 2; k <= 64; k <<= 1) {
        #pragma unroll
        for (int j = k >> 1; j >= 1; j >>= 1) {
            float ov = __shfl_xor(v, j);
            int   oi = __shfl_xor(ix, j);
            bool dirDesc = ((l & k) == 0);
            bool lower   = ((l & j) == 0);
            bool takeBetter = (lower == dirDesc);
            bool ob = kbetter(ov, oi, v, ix);
            if (takeBetter == ob) { v = ov; ix = oi; }
        }
    }
}

// ---------- double top-k (exact pass) ----------
__device__ __forceinline__ bool kbetterD(double v1, int i1, double v2, int i2) {
    return (v1 > v2) || (v1 == v2 && i1 < i2);
}

__device__ __forceinline__ void topk_insertD(double (&tv)[16], int (&ti)[16], double v, int idx) {
    if (!kbetterD(v, idx, tv[15], ti[15])) return;
    tv[15] = v; ti[15] = idx;
    #pragma unroll
    for (int s = 15; s >= 1; --s) {
        bool sw = kbetterD(tv[s], ti[s], tv[s-1], ti[s-1]);
        double av = sw ? tv[s] : tv[s-1];
        double bv = sw ? tv[s-1] : tv[s];
        int    ai = sw ? ti[s] : ti[s-1];
        int    bi = sw ? ti[s-1] : ti[s];
        tv[s-1] = av; tv[s] = bv; ti[s-1] = ai; ti[s] = bi;
    }
}

__device__ __forceinline__ void bitonic16D(double (&v)[16], int (&ix)[16]) {
    #pragma unroll
    for (int d = 8; d >= 1; d >>= 1) {
        #pragma unroll
        for (int i = 0; i < 16; ++i) {
            if ((i & d) == 0) {
                int j = i | d;
                bool sw = kbetterD(v[j], ix[j], v[i], ix[i]);
                double av = sw ? v[j] : v[i];
                double bv = sw ? v[i] : v[j];
                int    ai = sw ? ix[j] : ix[i];
                int    bi = sw ? ix[i] : ix[j];
                v[i] = av; v[j] = bv; ix[i] = ai; ix[j] = bi;
            }
        }
    }
}

__device__ __forceinline__ void lane_mergeD(double (&v)[16], int (&ix)[16], int mask) {
    double pv[16]; int pix[16];
    #pragma unroll
    for (int i = 0; i < 16; ++i) {
        pv[i]  = __shfl_xor(v[15 - i], mask);
        pix[i] = __shfl_xor(ix[15 - i], mask);
    }
    #pragma unroll
    for (int i = 0; i < 16; ++i) {
        if (kbetterD(pv[i], pix[i], v[i], ix[i])) { v[i] = pv[i]; ix[i] = pix[i]; }
    }
    bitonic16D(v, ix);
}

// ---------- kernel 0: normalize Q; fp16-hi fragment pack + fp32 rows ----------
// qpk layout: [ks(24)][qf(4)][lane(64)][8 halves]
__global__ __launch_bounds__(256)
void prep_kernel(const float* __restrict__ query, _Float16* __restrict__ qpk,
                 float* __restrict__ qn) {
    int b = blockIdx.x, t = threadIdx.x;
    const float* row = query + b * D;
    float vals[3]; float s = 0.f;
    #pragma unroll
    for (int j = 0; j < 3; ++j) { vals[j] = row[t + 256 * j]; s += vals[j] * vals[j]; }
    #pragma unroll
    for (int m = 1; m < 64; m <<= 1) s += __shfl_xor(s, m);
    __shared__ float ws4[4];
    if ((t & 63) == 0) ws4[t >> 6] = s;
    __syncthreads();
    float qnorm = sqrtf(ws4[0] + ws4[1] + ws4[2] + ws4[3]);
    int qf = b >> 4;
    #pragma unroll
    for (int j = 0; j < 3; ++j) {
        int col = t + 256 * j;
        float vn = vals[j] / qnorm;
        qn[b * D + col] = vn;
        int ks = col >> 5, unit = (col >> 3) & 3, sub = col & 7;
        int lane = (b & 15) + unit * 16;
        qpk[(((size_t)ks * 4 + qf) * 64 + lane) * 8 + sub] = (_Float16)vn;
    }
}

// ---------- kernel 1: sim pass-1 — contiguous stream, depth-2 prefetch,
//            vmcnt-preserving barriers, k-split across 16 waves ----------
__global__ __launch_bounds__(SIMTPB, 4)
void sim_kernel(const float* __restrict__ corpus,
                const _Float16* __restrict__ qpk,
                unsigned short* __restrict__ simout, int N, int NTILES) {
    extern __shared__ __align__(16) char smem[];
    const _Float16* qlds = (const _Float16*)smem;
    char*  tiles   = smem + LDS_TILE;
    float* scratch = (float*)(smem + LDS_SCR);
    float* cn      = (float*)(smem + LDS_CN);

    int t = threadIdx.x, w = t >> 6, l = t & 63;
    int qf = w & 3, kq = w >> 2;
    int row = w;          // staging: wave w owns corpus tile-row w
    int n16 = l & 15, kg = l >> 4;

    // stage Q pack once: 6144 16B granules, linear LDS dest
    #pragma unroll
    for (int j = 0; j < 6; ++j) {
        int idx = t + SIMTPB * j;
        __builtin_amdgcn_global_load_lds((gas_ptr)(const void*)(qpk + (size_t)idx * 8),
                                         (las_ptr)(void*)(smem + (size_t)idx * 16), 16, 0, 0);
    }

    int b = blockIdx.x;
    int q0 = NTILES / SIMGRID, r0 = NTILES % SIMGRID;
    int t0 = b * q0 + min(b, r0);
    int cnt = q0 + (b < r0 ? 1 : 0);

    auto LOADT = [&](int i, float4 (&R)[3]) {
        long g = (long)(t0 + i) * RT + row;
        if (g > N - 1) g = N - 1;
        const float* p = corpus + (size_t)g * D + l * 12;
        R[0] = *(const float4*)p;
        R[1] = *(const float4*)(p + 4);
        R[2] = *(const float4*)(p + 8);
    };

    // convert 12 staged floats -> fp16 tile (XOR-swizzled), accumulate row norm
    auto CVT = [&](float4 (&R)[3], int buf) {
        char* base = tiles + buf * TILE_B;
        float ps = 0.f;
        int swz = (row & 7) << 4;
        #pragma unroll
        for (int j = 0; j < 3; ++j) {
            float4 x = R[j];
            ps += x.x * x.x + x.y * x.y + x.z * x.z + x.w * x.w;
            h16x4 h;
            h.x = (_Float16)x.x; h.y = (_Float16)x.y;
            h.z = (_Float16)x.z; h.w = (_Float16)x.w;
            int off = row * 1536 + l * 24 + j * 8;
            *(h16x4*)(base + (off ^ swz)) = h;
        }
        #pragma unroll
        for (int m = 1; m < 64; m <<= 1) ps += __shfl_xor(ps, m);
        if (l == 0) cn[buf * RT + row] = ps;
    };

    auto BODY = [&](int i, float4 (&Rcons)[3], float4 (&Riss)[3]) {
        float cnv = cn[(i & 1) * RT + n16];       // hoisted before B1 (race-safe window)
        if (i + 2 < cnt) LOADT(i + 2, Riss);      // depth-2: stays in flight across barriers
        // compute this wave's k-quarter over the resident tile
        const char* base = tiles + (i & 1) * TILE_B;
        f32x4 acc = (f32x4)(0.f);
        int cswz = (n16 & 7) << 4;
        #pragma unroll
        for (int s = 0; s < 6; ++s) {
            int ks = kq * 6 + s;
            h16x8 qh = *(const h16x8*)(qlds + (((size_t)ks * 4 + qf) * 64 + l) * 8);
            int cb = n16 * 1536 + ks * 64 + kg * 16;
            h16x8 ch = *(const h16x8*)(base + (cb ^ cswz));
            acc = __builtin_amdgcn_mfma_f32_16x16x32_f16(qh, ch, acc, 0, 0, 0);
        }
        if (i + 1 < cnt) CVT(Rcons, (i + 1) & 1); // waits only Rcons vmcnt (older); Riss stays in flight
        asm volatile("s_waitcnt lgkmcnt(0)" ::: "memory");
        __builtin_amdgcn_s_barrier();             // B1: no vmcnt drain
        if (kq) *(f32x4*)(scratch + ((kq - 1) * 4 + qf) * 256 + l * 4) = acc;
        asm volatile("s_waitcnt lgkmcnt(0)" ::: "memory");
        __builtin_amdgcn_s_barrier();             // B2
        if (kq == 0) {
            #pragma unroll
            for (int p = 0; p < 3; ++p)
                acc += *(const f32x4*)(scratch + (p * 4 + qf) * 256 + l * 4);
            float inv = 1.0f / sqrtf(cnv);
            long n = (long)(t0 + i) * RT + n16;
            if (n < N) {
                ushort4 pk;
                pk.x = f2bf(acc[0] * inv); pk.y = f2bf(acc[1] * inv);
                pk.z = f2bf(acc[2] * inv); pk.w = f2bf(acc[3] * inv);
                *(ushort4*)(simout + n * NQ + qf * 16 + kg * 4) = pk;
            }
        }
    };

    float4 RA[3], RB[3];
    LOADT(0, RA);
    if (cnt > 1) LOADT(1, RB);
    CVT(RA, 0);
    __syncthreads();     // prologue: full drain OK (Q pack + tile 0 resident)

    int i = 0;
    while (i < cnt) {
        BODY(i, RB, RA); ++i;
        if (i < cnt) { BODY(i, RA, RB); ++i; }
    }
}

// ---------- kernel 2: stream bf16 sims -> per-wave per-query top-16 ----------
__global__ __launch_bounds__(256)
void mergeA_kernel(const unsigned short* __restrict__ simout, float2* __restrict__ candA, int N) {
    int t = threadIdx.x, w = t >> 6, l = t & 63;
    int ww = blockIdx.x * 4 + w;
    int chunk = (N + NMW - 1) / NMW;
    int n0 = ww * chunk, n1 = min(N, n0 + chunk);

    float tv[16]; int ti[16];
    #pragma unroll
    for (int s = 0; s < 16; ++s) { tv[s] = -INFINITY; ti[s] = 0x7fffffff; }

    int n = n0;
    for (; n + 8 <= n1; n += 8) {
        float v[8];
        #pragma unroll
        for (int j = 0; j < 8; ++j) v[j] = bf2f(simout[(size_t)(n + j) * NQ + l]);
        #pragma unroll
        for (int j = 0; j < 8; ++j) topk_insert(tv, ti, v[j], n + j);
    }
    for (; n < n1; ++n) topk_insert(tv, ti, bf2f(simout[(size_t)n * NQ + l]), n);

    float2* dst = candA + ((size_t)l * NMW + ww) * 16;
    #pragma unroll
    for (int s = 0; s < 16; ++s) dst[s] = make_float2(tv[s], __int_as_float(ti[s]));
}

// ---------- kernel 3: partial merge — 8 segments per query ----------
__global__ __launch_bounds__(256)
void merge1_kernel(const float2* __restrict__ cand, float2* __restrict__ cand2, int NWV) {
    int q = blockIdx.x >> 3, seg = blockIdx.x & (NS - 1);
    int t = threadIdx.x, w = t >> 6, l = t & 63;
    int total = NWV * 16;
    int chunk = (total + NS - 1) / NS;
    int e0 = seg * chunk, e1 = min(total, e0 + chunk);
    const float2* src = cand + (size_t)q * total;
    float tv[16]; int ti[16];
    #pragma unroll
    for (int s = 0; s < 16; ++s) { tv[s] = -INFINITY; ti[s] = 0x7fffffff; }
    for (int e = e0 + t; e < e1; e += 256) {
        float2 ce = src[e];
        topk_insert(tv, ti, ce.x, __float_as_int(ce.y));
    }
    lane_merge(tv, ti, 1);  lane_merge(tv, ti, 2);  lane_merge(tv, ti, 4);
    lane_merge(tv, ti, 8);  lane_merge(tv, ti, 16); lane_merge(tv, ti, 32);
    __shared__ float2 stage[64];
    if (l == 0) {
        #pragma unroll
        for (int s = 0; s < 16; ++s) stage[w * 16 + s] = make_float2(tv[s], __int_as_float(ti[s]));
    }
    __syncthreads();
    if (t < 64) {
        float2 ce = stage[t];
        float v = ce.x; int ix = __float_as_int(ce.y);
        sort64(v, ix, t);
        if (t < 16) cand2[((size_t)q * NS + seg) * 16 + t] = make_float2(v, __int_as_float(ix));
    }
}

// ---------- kernel 4: approx top-16 -> per-query threshold; zero counters ----------
__global__ __launch_bounds__(64)
void merge2t_kernel(const float2* __restrict__ cand2, float* __restrict__ thr,
                    int* __restrict__ cnt) {
    int q = blockIdx.x, l = threadIdx.x;
    const float2* src = cand2 + (size_t)q * (NS * 16);
    float2 a = src[l], b = src[l + 64];
    float v1 = a.x; int i1 = __float_as_int(a.y);
    float v2 = b.x; int i2 = __float_as_int(b.y);
    sort64(v1, i1, l);
    sort64(v2, i2, l);
    float sv = __shfl(v2, (l - 16) & 63);
    int   si = __shfl(i2, (l - 16) & 63);
    float mv = (l < 16) ? v1 : ((l < 32) ? sv : -INFINITY);
    int   mi = (l < 16) ? i1 : ((l < 32) ? si : 0x7fffffff);
    sort64(mv, mi, l);
    if (l == 15) {
        thr[q] = mv - MARGIN;
        cnt[q] = 0;
    }
}

// ---------- kernel 5: filter — candidates above threshold ----------
__global__ __launch_bounds__(256)
void filter_kernel(const unsigned short* __restrict__ simout, const float* __restrict__ thr,
                   int* __restrict__ cnt, int* __restrict__ candx, int N) {
    int t = threadIdx.x, w = t >> 6, l = t & 63;
    int wid = blockIdx.x * 4 + w;
    int nwaves = gridDim.x * 4;
    float th = thr[l];
    for (int n = wid; n < N; n += nwaves) {
        float v = bf2f(simout[(size_t)n * NQ + l]);
        if (v >= th) {
            int s = atomicAdd(&cnt[l], 1);
            if (s < CANDCAP) candx[l * CANDCAP + s] = n;
        }
    }
}

// ---------- kernel 6: exact fp64 re-rank ----------
__global__ __launch_bounds__(256)
void exact_kernel(const float* __restrict__ corpus, const float* __restrict__ qn,
                  const int* __restrict__ cnt, const int* __restrict__ candx,
                  float* __restrict__ out, int N) {
    int q = blockIdx.x, t = threadIdx.x, w = t >> 6, l = t & 63;
    int m = min(cnt[q], CANDCAP);
    __shared__ double vals[CANDCAP];
    __shared__ int    idxs[CANDCAP];

    const float* qr = qn + q * D;
    for (int c = w; c < m; c += 4) {
        int n = candx[q * CANDCAP + c];
        const float* cr = corpus + (size_t)n * D;
        double acc = 0.0, cs = 0.0;
        #pragma unroll
        for (int j = 0; j < D / 64; ++j) {
            double cv = (double)cr[l + j * 64];
            acc += (double)qr[l + j * 64] * cv;
            cs  += cv * cv;
        }
        #pragma unroll
        for (int msk = 1; msk < 64; msk <<= 1) {
            acc += __shfl_xor(acc, msk);
            cs  += __shfl_xor(cs, msk);
        }
        if (l == 0) { vals[c] = acc / sqrt(cs); idxs[c] = n; }
    }
    __syncthreads();

    if (w == 0) {
        double tv[16]; int ti[16];
        #pragma unroll
        for (int s = 0; s < 16; ++s) { tv[s] = -1e300; ti[s] = 0x7fffffff; }
        for (int r = 0; r < CANDCAP / 64; ++r) {
            int e = l + r * 64;
            if (e < m) topk_insertD(tv, ti, vals[e], idxs[e]);
        }
        lane_mergeD(tv, ti, 1);  lane_mergeD(tv, ti, 2);  lane_mergeD(tv, ti, 4);
        lane_mergeD(tv, ti, 8);  lane_mergeD(tv, ti, 16); lane_mergeD(tv, ti, 32);
        if (l == 0) {
            #pragma unroll
            for (int s = 0; s < 16; ++s) {
                out[q * 16 + s]           = (float)tv[s];
                out[NQ * 16 + q * 16 + s] = (float)ti[s];
            }
        }
    }
}

extern "C" void kernel_launch(void* const* d_in, const int* in_sizes, int n_in,
                              void* d_out, int out_size, void* d_ws, size_t ws_size,
                              hipStream_t stream) {
    const float* query  = (const float*)d_in[0];
    const float* corpus = (const float*)d_in[1];
    int N      = in_sizes[1] / D;                 // 500000
    int NTILES = (N + RT - 1) / RT;               // 31250

    char* ws = (char*)d_ws;
    _Float16* qpk = (_Float16*)ws;                              // 98304 B
    float* qn     = (float*)(ws + 98304);                       // 196608 B
    unsigned short* simout = (unsigned short*)(ws + 98304 + 196608);   // 64 MB
    size_t simBytes = (size_t)NTILES * RT * NQ * sizeof(unsigned short);
    char* p = ws + 98304 + 196608 + simBytes;
    float2* candA = (float2*)p;                                 // 33.5 MB
    size_t candABytes = (size_t)NQ * NMW * 16 * sizeof(float2);
    float2* cand2 = (float2*)(p + candABytes);                  // 64 KB
    float*  thr   = (float*)(p + candABytes + 65536);           // 256 B
    int*    cnt   = (int*)(p + candABytes + 65536 + 256);       // 256 B
    int*    candx = (int*)(p + candABytes + 65536 + 512);       // 64 KB
    float* out = (float*)d_out;

    (void)hipFuncSetAttribute((const void*)sim_kernel,
                              hipFuncAttributeMaxDynamicSharedMemorySize, LDS_BYTES);

    prep_kernel<<<NQ, 256, 0, stream>>>(query, qpk, qn);
    sim_kernel<<<SIMGRID, SIMTPB, LDS_BYTES, stream>>>(corpus, qpk, simout, N, NTILES);
    mergeA_kernel<<<NMW / 4, 256, 0, stream>>>(simout, candA, N);
    merge1_kernel<<<NQ * NS, 256, 0, stream>>>(candA, cand2, NMW);
    merge2t_kernel<<<NQ, 64, 0, stream>>>(cand2, thr, cnt);
    filter_kernel<<<1024, 256, 0, stream>>>(simout, thr, cnt, candx, N);
    exact_kernel<<<NQ, 256, 0, stream>>>(corpus, qn, cnt, candx, out, N);
}